// Round 5
// baseline (130.080 us; speedup 1.0000x reference)
//
#include <hip/hip_runtime.h>
#include <hip/hip_bf16.h>
#include <stdint.h>

using bf16 = __hip_bfloat16;
typedef __attribute__((ext_vector_type(8))) short bf16x8;   // 8 bf16 = 4 VGPRs
typedef __attribute__((ext_vector_type(4))) float f32x4;

static __device__ __forceinline__ float b2f(short u) {
  union { float f; unsigned int i; } c;
  c.i = ((unsigned int)(unsigned short)u) << 16;
  return c.f;
}
static __device__ __forceinline__ short f2b(float f) {
  return (short)__bfloat16_as_ushort(__float2bfloat16(f));
}

// compiler-level memory fence (stop IR motion of LDS ops across barriers)
static __device__ __forceinline__ void cfence() {
  asm volatile("" ::: "memory");
}

// ---------------------------------------------------------------------------
// async global->LDS, 16B per lane (global_load_lds_dwordx4).
// ---------------------------------------------------------------------------
__device__ __forceinline__ void async16(const void* g, void* lds) {
  __builtin_amdgcn_global_load_lds(
      (const __attribute__((address_space(1))) void*)g,
      (__attribute__((address_space(3))) void*)lds, 16, 0, 0);
}

// ---------------------------------------------------------------------------
// Kron-expanded DOWN weight, transposed bf16: wdT[n][k], n<512, k<2048
// ---------------------------------------------------------------------------
__global__ void build_wdT(const float* __restrict__ phm,
                          const float* __restrict__ Wd,
                          bf16* __restrict__ out) {
  int idx = blockIdx.x * 256 + threadIdx.x;
  if (idx >= 512 * 2048) return;
  int n = idx >> 11, k = idx & 2047;
  int r = n >> 7, s = n & 127;
  int p = k >> 9, q = k & 511;
  float v = 0.f;
#pragma unroll
  for (int i = 0; i < 4; ++i)
    v += phm[i * 16 + p * 4 + r] * Wd[i * 65536 + q * 128 + s];
  out[idx] = (bf16)v;
}

// ---------------------------------------------------------------------------
// Kron-expanded UP weight, transposed bf16: wuT[d][b], d<2048, b<512
// ---------------------------------------------------------------------------
__global__ void build_wuT(const float* __restrict__ phm,
                          const float* __restrict__ Wu,
                          bf16* __restrict__ out) {
  int idx = blockIdx.x * 256 + threadIdx.x;
  if (idx >= 2048 * 512) return;
  int d = idx >> 9, b = idx & 511;
  int r = d >> 9, s = d & 511;
  int p = b >> 7, q = b & 127;
  float v = 0.f;
#pragma unroll
  for (int i = 0; i < 4; ++i)
    v += phm[i * 16 + p * 4 + r] * Wu[i * 65536 + q * 512 + s];
  out[idx] = (bf16)v;
}

// ---------------------------------------------------------------------------
// x (f32) -> bf16
// ---------------------------------------------------------------------------
__global__ void cast_f32_bf16(const float* __restrict__ in,
                              bf16* __restrict__ out, int n4) {
  int i = blockIdx.x * 256 + threadIdx.x;
  if (i >= n4) return;
  float4 v = reinterpret_cast<const float4*>(in)[i];
  ushort4 o;
  o.x = __bfloat16_as_ushort(__float2bfloat16(v.x));
  o.y = __bfloat16_as_ushort(__float2bfloat16(v.y));
  o.z = __bfloat16_as_ushort(__float2bfloat16(v.z));
  o.w = __bfloat16_as_ushort(__float2bfloat16(v.w));
  reinterpret_cast<ushort4*>(out)[i] = o;
}

// ---------------------------------------------------------------------------
// z = relu(sum_c P[c] + b_down) -> bf16.   P: 4 x [8192][512] bf16 partials
// ---------------------------------------------------------------------------
__global__ void zred(const bf16* __restrict__ P, const float* __restrict__ bias,
                     bf16* __restrict__ z) {
  int i = blockIdx.x * 256 + threadIdx.x;        // vec8 index
  const int NV = 8192 * 512 / 8;
  if (i >= NV) return;
  const size_t CS = (size_t)NV;                  // chunk stride in vec8 units
  bf16x8 v0 = ((const bf16x8*)P)[i];
  bf16x8 v1 = ((const bf16x8*)P)[i + CS];
  bf16x8 v2 = ((const bf16x8*)P)[i + 2 * CS];
  bf16x8 v3 = ((const bf16x8*)P)[i + 3 * CS];
  int c0 = (i * 8) & 511;
  bf16x8 o;
#pragma unroll
  for (int j = 0; j < 8; ++j) {
    float t = b2f(v0[j]) + b2f(v1[j]) + b2f(v2[j]) + b2f(v3[j]) + bias[c0 + j];
    o[j] = f2b(t > 0.f ? t : 0.f);
  }
  ((bf16x8*)z)[i] = o;
}

// ---------------------------------------------------------------------------
// C = A * Bt^T (+bias).  256x256 tile, BK=32, 8 waves (2Mx4N), per-wave
// 128x64 output = acc[8][4] 16x16 fragments.
// T4 schedule: double-buffered LDS, counted vmcnt (never drain to 0 in the
// main loop), raw s_barrier. Per iter:
//   compute buf[cur] -> barrier (reads done) -> STAGE(t+2) into buf[cur]
//   -> vmcnt(4) (t+1's loads landed, t+2's in flight) -> barrier -> swap.
// EPI=0: bias+relu -> bf16 ; EPI=1: bias -> f32 ; EPI=2: raw -> bf16 partial
// Grid linear, bijective XCD swizzle (gridDim.x % 8 == 0).
// ---------------------------------------------------------------------------
template <int EPI>
__global__ __launch_bounds__(512, 2)
void gemm_bt(const bf16* __restrict__ A, const bf16* __restrict__ Bt,
             const float* __restrict__ bias, void* __restrict__ Cout,
             int lda, int ldb, int Klen, int N, int nbx, int nby,
             size_t cStrideBytes) {
  constexpr int BM = 256, BN = 256, BK = 32;
  __shared__ bf16 Ash[2][BM * BK];   // 2 x 16 KB
  __shared__ bf16 Bsh[2][BN * BK];   // 2 x 16 KB

  // XCD swizzle (bijective: gridDim.x multiple of 8)
  int bid = blockIdx.x;
  int qq = gridDim.x >> 3;
  bid = (bid & 7) * qq + (bid >> 3);
  const int bx = bid % nbx;
  const int t1 = bid / nbx;
  const int by = t1 % nby;
  const int chunk = t1 / nby;
  const int bm = bx * BM;
  const int bn = by * BN;
  const int koff = chunk * Klen;
  char* Cb = (char*)Cout + (size_t)chunk * cStrideBytes;

  const int tid  = threadIdx.x;          // 0..511
  const int lane = tid & 63;
  const int wave = tid >> 6;             // 0..7
  const int wm = (wave >> 2) * 128;      // 2 wave-rows
  const int wn = (wave & 3) * 64;        // 4 wave-cols
  const int rl = lane & 15;
  const int sw = lane >> 4;

  f32x4 acc[8][4] = {};

  // staging: 256 rows x 4 slots of 16B = 1024 idx; 512 threads -> 2 iters
  // 4 global_load_lds per thread per STAGE.
#define STAGE(buf, kk)                                                        \
  {                                                                           \
    _Pragma("unroll")                                                         \
    for (int is = 0; is < 2; ++is) {                                          \
      int idx = is * 512 + tid;                                               \
      int r = idx >> 2, s = idx & 3;                                          \
      async16(A + (size_t)(bm + r) * lda + (kk) + ((s ^ (r & 3)) * 8),        \
              &Ash[buf][idx * 8]);                                            \
    }                                                                         \
    _Pragma("unroll")                                                         \
    for (int is = 0; is < 2; ++is) {                                          \
      int idx = is * 512 + tid;                                               \
      int r = idx >> 2, s = idx & 3;                                          \
      async16(Bt + (size_t)(bn + r) * ldb + (kk) + ((s ^ (r & 3)) * 8),       \
              &Bsh[buf][idx * 8]);                                            \
    }                                                                         \
  }

  const int nt = Klen / BK;   // >= 2 always here

  // prologue: stage tiles 0 and 1; wait tile 0 only (tile 1 stays in flight)
  STAGE(0, koff);
  STAGE(1, koff + BK);
  asm volatile("s_waitcnt vmcnt(4)" ::: "memory");
  cfence(); __builtin_amdgcn_s_barrier(); cfence();
  __builtin_amdgcn_sched_barrier(0);

  int cur = 0;
  for (int t = 0; t < nt; ++t) {
    bf16x8 af[8], bfr[4];
#pragma unroll
    for (int m = 0; m < 8; ++m) {
      int rr = wm + m * 16 + rl;
      af[m] = *(const bf16x8*)(&Ash[cur][rr * BK + ((sw ^ (rl & 3)) * 8)]);
    }
#pragma unroll
    for (int n = 0; n < 4; ++n) {
      int rr = wn + n * 16 + rl;
      bfr[n] = *(const bf16x8*)(&Bsh[cur][rr * BK + ((sw ^ (rl & 3)) * 8)]);
    }

    __builtin_amdgcn_s_setprio(1);
#pragma unroll
    for (int m = 0; m < 8; ++m)
#pragma unroll
      for (int n = 0; n < 4; ++n)
        acc[m][n] = __builtin_amdgcn_mfma_f32_16x16x32_bf16(af[m], bfr[n],
                                                            acc[m][n], 0, 0, 0);
    __builtin_amdgcn_s_setprio(0);

    // all waves done reading buf[cur]
    cfence(); __builtin_amdgcn_s_barrier(); cfence();
    __builtin_amdgcn_sched_barrier(0);

    if (t + 2 < nt) {
      STAGE(cur, koff + (t + 2) * BK);   // reuse just-freed buffer
      asm volatile("s_waitcnt vmcnt(4)" ::: "memory");  // t+1's loads landed
    } else {
      asm volatile("s_waitcnt vmcnt(0)" ::: "memory");  // tail: drain
    }
    // all waves' loads for buf[cur^1] have landed
    cfence(); __builtin_amdgcn_s_barrier(); cfence();
    __builtin_amdgcn_sched_barrier(0);

    cur ^= 1;
  }
#undef STAGE

  // C/D layout: col = lane&15, row = (lane>>4)*4 + j
  const int rq = sw * 4;
#pragma unroll
  for (int n = 0; n < 4; ++n) {
    int gc = bn + wn + n * 16 + rl;
    float bv = (EPI == 2) ? 0.f : bias[gc];
#pragma unroll
    for (int m = 0; m < 8; ++m) {
      int gr0 = bm + wm + m * 16 + rq;
#pragma unroll
      for (int j = 0; j < 4; ++j) {
        float v = acc[m][n][j] + bv;
        if constexpr (EPI == 0) {
          v = v > 0.f ? v : 0.f;
          ((bf16*)Cb)[(size_t)(gr0 + j) * N + gc] = __float2bfloat16(v);
        } else if constexpr (EPI == 1) {
          ((float*)Cb)[(size_t)(gr0 + j) * N + gc] = v;
        } else {
          ((bf16*)Cb)[(size_t)(gr0 + j) * N + gc] = __float2bfloat16(v);
        }
      }
    }
  }
}

// ---------------------------------------------------------------------------
extern "C" void kernel_launch(void* const* d_in, const int* in_sizes, int n_in,
                              void* d_out, int out_size, void* d_ws, size_t ws_size,
                              hipStream_t stream) {
  const float* x      = (const float*)d_in[0];   // [8192,2048]
  const float* phm    = (const float*)d_in[1];   // [4,4,4]
  const float* W_down = (const float*)d_in[2];   // [4,512,128]
  const float* b_down = (const float*)d_in[3];   // [512]
  const float* W_up   = (const float*)d_in[4];   // [4,128,512]
  const float* b_up   = (const float*)d_in[5];   // [2048]
  float* out = (float*)d_out;                    // [8192,2048] f32

  const int T = 8192, D = 2048, B = 512;
  const size_t MB = 1024 * 1024;

  char* ws = (char*)d_ws;
  bf16* xb  = (bf16*)(ws);                 // 32 MB  [8192][2048]
  bf16* wdT = (bf16*)(ws + 32 * MB);       //  2 MB  [512][2048]
  bf16* wuT = (bf16*)(ws + 34 * MB);       //  2 MB  [2048][512]
  bf16* z   = (bf16*)(ws + 36 * MB);       //  8 MB  [8192][512]
  bf16* P   = (bf16*)(ws + 44 * MB);       // 32 MB  4 x [8192][512] partials

  // prep
  cast_f32_bf16<<<dim3((T * D / 4 + 255) / 256), dim3(256), 0, stream>>>(x, xb, T * D / 4);
  build_wdT<<<dim3((B * D + 255) / 256), dim3(256), 0, stream>>>(phm, W_down, wdT);
  build_wuT<<<dim3((D * B + 255) / 256), dim3(256), 0, stream>>>(phm, W_up, wuT);

  if (ws_size >= 76 * MB) {
    // GEMM1 split-K x4: P[c] = x @ Wd (K chunk c). grid 32x2x4 = 256
    gemm_bt<2><<<dim3(256), dim3(512), 0, stream>>>(
        xb, wdT, b_down, P, D, D, 512, B, 32, 2, (size_t)T * B * sizeof(bf16));
    // z = relu(sum P + b_down)
    zred<<<dim3(T * B / 8 / 256), dim3(256), 0, stream>>>(P, b_down, z);
  } else {
    // fallback: single-pass GEMM1, grid 32x2 = 64
    gemm_bt<0><<<dim3(64), dim3(512), 0, stream>>>(
        xb, wdT, b_down, z, D, D, D, B, 32, 2, 0);
  }

  // out = z @ Wu + b_up   [8192,2048] f32, grid 32x8 = 256
  gemm_bt<1><<<dim3(256), dim3(512), 0, stream>>>(
      z, wuT, b_up, out, B, B, B, D, 32, 8, 0);
}

// Round 6
// 122.897 us; speedup vs baseline: 1.0584x; 1.0584x over previous
//
#include <hip/hip_runtime.h>
#include <hip/hip_bf16.h>
#include <stdint.h>

using bf16 = __hip_bfloat16;
typedef __attribute__((ext_vector_type(8))) short bf16x8;   // 8 bf16 = 4 VGPRs
typedef __attribute__((ext_vector_type(4))) float f32x4;

static __device__ __forceinline__ float b2f(short u) {
  union { float f; unsigned int i; } c;
  c.i = ((unsigned int)(unsigned short)u) << 16;
  return c.f;
}
static __device__ __forceinline__ short f2b(float f) {
  return (short)__bfloat16_as_ushort(__float2bfloat16(f));
}

// compiler-level memory fence (stop IR motion of memory ops across segments)
static __device__ __forceinline__ void cfence() { asm volatile("" ::: "memory"); }
static __device__ __forceinline__ void bar()    { cfence(); __builtin_amdgcn_s_barrier(); cfence(); }

__device__ __forceinline__ void async16(const void* g, void* lds) {
  __builtin_amdgcn_global_load_lds(
      (const __attribute__((address_space(1))) void*)g,
      (__attribute__((address_space(3))) void*)lds, 16, 0, 0);
}

// ---------------------------------------------------------------------------
// Kron-expanded DOWN weight, transposed bf16: wdT[n][k], n<512, k<2048
// ---------------------------------------------------------------------------
__global__ void build_wdT(const float* __restrict__ phm,
                          const float* __restrict__ Wd,
                          bf16* __restrict__ out) {
  int idx = blockIdx.x * 256 + threadIdx.x;
  if (idx >= 512 * 2048) return;
  int n = idx >> 11, k = idx & 2047;
  int r = n >> 7, s = n & 127;
  int p = k >> 9, q = k & 511;
  float v = 0.f;
#pragma unroll
  for (int i = 0; i < 4; ++i)
    v += phm[i * 16 + p * 4 + r] * Wd[i * 65536 + q * 128 + s];
  out[idx] = (bf16)v;
}

// ---------------------------------------------------------------------------
// Kron-expanded UP weight, transposed bf16: wuT[d][b], d<2048, b<512
// ---------------------------------------------------------------------------
__global__ void build_wuT(const float* __restrict__ phm,
                          const float* __restrict__ Wu,
                          bf16* __restrict__ out) {
  int idx = blockIdx.x * 256 + threadIdx.x;
  if (idx >= 2048 * 512) return;
  int d = idx >> 9, b = idx & 511;
  int r = d >> 9, s = d & 511;
  int p = b >> 7, q = b & 127;
  float v = 0.f;
#pragma unroll
  for (int i = 0; i < 4; ++i)
    v += phm[i * 16 + p * 4 + r] * Wu[i * 65536 + q * 512 + s];
  out[idx] = (bf16)v;
}

// ---------------------------------------------------------------------------
// x (f32) -> bf16
// ---------------------------------------------------------------------------
__global__ void cast_f32_bf16(const float* __restrict__ in,
                              bf16* __restrict__ out, int n4) {
  int i = blockIdx.x * 256 + threadIdx.x;
  if (i >= n4) return;
  float4 v = reinterpret_cast<const float4*>(in)[i];
  ushort4 o;
  o.x = __bfloat16_as_ushort(__float2bfloat16(v.x));
  o.y = __bfloat16_as_ushort(__float2bfloat16(v.y));
  o.z = __bfloat16_as_ushort(__float2bfloat16(v.z));
  o.w = __bfloat16_as_ushort(__float2bfloat16(v.w));
  reinterpret_cast<ushort4*>(out)[i] = o;
}

// ---------------------------------------------------------------------------
// z = relu(sum_c P[c] + b_down) -> bf16.   P: 4 x [8192][512] bf16 partials
// ---------------------------------------------------------------------------
__global__ void zred(const bf16* __restrict__ P, const float* __restrict__ bias,
                     bf16* __restrict__ z) {
  int i = blockIdx.x * 256 + threadIdx.x;        // vec8 index
  const int NV = 8192 * 512 / 8;
  if (i >= NV) return;
  const size_t CS = (size_t)NV;
  bf16x8 v0 = ((const bf16x8*)P)[i];
  bf16x8 v1 = ((const bf16x8*)P)[i + CS];
  bf16x8 v2 = ((const bf16x8*)P)[i + 2 * CS];
  bf16x8 v3 = ((const bf16x8*)P)[i + 3 * CS];
  int c0 = (i * 8) & 511;
  bf16x8 o;
#pragma unroll
  for (int j = 0; j < 8; ++j) {
    float t = b2f(v0[j]) + b2f(v1[j]) + b2f(v2[j]) + b2f(v3[j]) + bias[c0 + j];
    o[j] = f2b(t > 0.f ? t : 0.f);
  }
  ((bf16x8*)z)[i] = o;
}

// ---------------------------------------------------------------------------
// 8-phase 256x256 GEMM, BK=64. C = A * Bt^T (+bias).
// 8 waves (2M x 4N), per-wave 128x64 output = acc[8][4].
// LDS: per K-tile, A/B each split in 2 halves of [128][64] bf16 (16KB);
// double-buffered => 128KB. Slot swizzle: 16B slot s at row r holds global
// slot s^(r&7) (pre-swizzled source, linear LDS dest; read applies same XOR)
// => every ds_read_b128 is the optimal 8 bank-cycles.
// Phases per K-tile t (buffers: tile t in buf[t&1]):
//  P0: read af[0..3][ks], bf[0..1][ks]; stage B-half0(t+1); bar; 16 MFMA; bar
//  P1: read bf[2..3][ks];               stage B-half1(t+1); bar; 16 MFMA; bar
//  P2: read af[4..7][ks];                                   bar; 16 MFMA; bar
//  P3: (read-free) stage A-half0,1(t+2); s_waitcnt vmcnt(4); bar; 16 MFMA; bar
// Race-safety: B(t+1) writes buf[(t+1)&1] (not read during t); A(t+2) writes
// buf[t&1] only after its last read (P2) + barrier; vmcnt(4) at P3 drains
// everything except A(t+2)'s own 4 loads => tile t+1 fully landed.
// EPI=0: bias+relu -> bf16 ; EPI=1: bias -> f32 ; EPI=2: raw -> bf16 partial
// ---------------------------------------------------------------------------
template <int EPI>
__global__ __launch_bounds__(512, 2)
void gemm8p(const bf16* __restrict__ A, const bf16* __restrict__ Bt,
            const float* __restrict__ bias, void* __restrict__ Cout,
            int lda, int ldb, int Klen, int N, int nbx, int nby,
            size_t cStrideBytes) {
  constexpr int BM = 256, BN = 256, BK = 64;
  __shared__ bf16 Ash[2][2][128 * 64];   // [buf][half]  64 KB
  __shared__ bf16 Bsh[2][2][128 * 64];   // [buf][half]  64 KB

  // bijective XCD swizzle (gridDim.x % 8 == 0)
  int bid = blockIdx.x;
  int qq = gridDim.x >> 3;
  bid = (bid & 7) * qq + (bid >> 3);
  const int bx = bid % nbx;
  const int t1 = bid / nbx;
  const int by = t1 % nby;
  const int chunk = t1 / nby;
  const int bm = bx * BM;
  const int bn = by * BN;
  const int koff = chunk * Klen;
  char* Cb = (char*)Cout + (size_t)chunk * cStrideBytes;

  const int tid  = threadIdx.x;          // 0..511
  const int lane = tid & 63;
  const int wave = tid >> 6;             // 0..7
  const int wmh  = wave >> 2;            // A-half (0/1): rows wmh*128..+127
  const int wn   = wave & 3;             // B 64-col group
  const int wnh  = wn >> 1;              // B-half
  const int brow = (wn & 1) * 64;        // row base within B-half
  const int rl   = lane & 15;
  const int sw   = lane >> 4;            // 0..3
  const int sx   = rl & 7;               // row-dependent slot XOR

  f32x4 acc[8][4] = {};

#define STAGE_A(tt, h)                                                        \
  { _Pragma("unroll")                                                         \
    for (int is = 0; is < 2; ++is) {                                          \
      int idx = is * 512 + tid;                                               \
      int r = idx >> 3, sl = idx & 7;                                         \
      async16(A + (size_t)(bm + (h) * 128 + r) * lda + koff + (tt) * BK       \
                  + ((sl ^ (r & 7)) * 8),                                     \
              &Ash[(tt) & 1][h][idx * 8]);                                    \
    } }
#define STAGE_B(tt, h)                                                        \
  { _Pragma("unroll")                                                         \
    for (int is = 0; is < 2; ++is) {                                          \
      int idx = is * 512 + tid;                                               \
      int r = idx >> 3, sl = idx & 7;                                         \
      async16(Bt + (size_t)(bn + (h) * 128 + r) * ldb + koff + (tt) * BK      \
                  + ((sl ^ (r & 7)) * 8),                                     \
              &Bsh[(tt) & 1][h][idx * 8]);                                    \
    } }

  const int nt = Klen / BK;   // 8 (split chunks / GEMM2) or 32 (fallback)

  // prologue: tile0 complete + tile1 A-halves; leave tile1 A in flight
  STAGE_A(0, 0); STAGE_A(0, 1);
  STAGE_B(0, 0); STAGE_B(0, 1);
  STAGE_A(1, 0); STAGE_A(1, 1);
  asm volatile("s_waitcnt vmcnt(4)" ::: "memory");
  bar();

  bf16x8 af[8][2], bf[4][2];

  for (int t = 0; t < nt; ++t) {
    const int cur = t & 1;
    const bf16* __restrict__ Acur = &Ash[cur][wmh][0];
    const bf16* __restrict__ Bcur = &Bsh[cur][wnh][0];

#define LDA(m, ks) af[m][ks] = *(const bf16x8*)(Acur + ((m)*16 + rl) * 64 + ((((ks)*4 + sw) ^ sx) * 8))
#define LDB(n, ks) bf[n][ks] = *(const bf16x8*)(Bcur + (brow + (n)*16 + rl) * 64 + ((((ks)*4 + sw) ^ sx) * 8))
#define QUAD(M0, N0)                                                          \
  __builtin_amdgcn_s_setprio(1);                                              \
  _Pragma("unroll") for (int m = 0; m < 4; ++m)                               \
  _Pragma("unroll") for (int n = 0; n < 2; ++n)                               \
  _Pragma("unroll") for (int ks = 0; ks < 2; ++ks)                            \
    acc[(M0) + m][(N0) + n] = __builtin_amdgcn_mfma_f32_16x16x32_bf16(        \
        af[(M0) + m][ks], bf[(N0) + n][ks], acc[(M0) + m][(N0) + n], 0, 0, 0);\
  __builtin_amdgcn_s_setprio(0);

    // ---- P0 ----
    LDA(0, 0); LDA(0, 1); LDA(1, 0); LDA(1, 1);
    LDA(2, 0); LDA(2, 1); LDA(3, 0); LDA(3, 1);
    LDB(0, 0); LDB(0, 1); LDB(1, 0); LDB(1, 1);
    cfence();
    if (t + 1 < nt) STAGE_B(t + 1, 0);
    bar();
    QUAD(0, 0);
    bar();
    // ---- P1 ----
    LDB(2, 0); LDB(2, 1); LDB(3, 0); LDB(3, 1);
    cfence();
    if (t + 1 < nt) STAGE_B(t + 1, 1);
    bar();
    QUAD(0, 2);
    bar();
    // ---- P2 ----
    LDA(4, 0); LDA(4, 1); LDA(5, 0); LDA(5, 1);
    LDA(6, 0); LDA(6, 1); LDA(7, 0); LDA(7, 1);
    cfence();
    bar();
    QUAD(4, 0);
    bar();
    // ---- P3 (read-free) ----
    if (t + 2 < nt) {
      STAGE_A(t + 2, 0); STAGE_A(t + 2, 1);
      asm volatile("s_waitcnt vmcnt(4)" ::: "memory");
    } else if (t + 1 < nt) {
      asm volatile("s_waitcnt vmcnt(0)" ::: "memory");
    }
    bar();
    QUAD(4, 2);
    if (t + 1 < nt) bar();

#undef LDA
#undef LDB
#undef QUAD
  }
#undef STAGE_A
#undef STAGE_B

  // Epilogue. C/D layout: col = lane&15, row = (lane>>4)*4 + j
  const int rq = sw * 4;
#pragma unroll
  for (int n = 0; n < 4; ++n) {
    int gc = bn + wn * 64 + n * 16 + rl;
    float bv = (EPI == 2) ? 0.f : bias[gc];
#pragma unroll
    for (int m = 0; m < 8; ++m) {
      int gr0 = bm + wmh * 128 + m * 16 + rq;
#pragma unroll
      for (int j = 0; j < 4; ++j) {
        float v = acc[m][n][j] + bv;
        if constexpr (EPI == 0) {
          v = v > 0.f ? v : 0.f;
          ((bf16*)Cb)[(size_t)(gr0 + j) * N + gc] = __float2bfloat16(v);
        } else if constexpr (EPI == 1) {
          ((float*)Cb)[(size_t)(gr0 + j) * N + gc] = v;
        } else {
          ((bf16*)Cb)[(size_t)(gr0 + j) * N + gc] = __float2bfloat16(v);
        }
      }
    }
  }
}

// ---------------------------------------------------------------------------
extern "C" void kernel_launch(void* const* d_in, const int* in_sizes, int n_in,
                              void* d_out, int out_size, void* d_ws, size_t ws_size,
                              hipStream_t stream) {
  const float* x      = (const float*)d_in[0];   // [8192,2048]
  const float* phm    = (const float*)d_in[1];   // [4,4,4]
  const float* W_down = (const float*)d_in[2];   // [4,512,128]
  const float* b_down = (const float*)d_in[3];   // [512]
  const float* W_up   = (const float*)d_in[4];   // [4,128,512]
  const float* b_up   = (const float*)d_in[5];   // [2048]
  float* out = (float*)d_out;                    // [8192,2048] f32

  const int T = 8192, D = 2048, B = 512;
  const size_t MB = 1024 * 1024;

  char* ws = (char*)d_ws;
  bf16* xb  = (bf16*)(ws);                 // 32 MB  [8192][2048]
  bf16* wdT = (bf16*)(ws + 32 * MB);       //  2 MB  [512][2048]
  bf16* wuT = (bf16*)(ws + 34 * MB);       //  2 MB  [2048][512]
  bf16* z   = (bf16*)(ws + 36 * MB);       //  8 MB  [8192][512]
  bf16* P   = (bf16*)(ws + 44 * MB);       // 32 MB  4 x [8192][512] partials

  // prep
  cast_f32_bf16<<<dim3((T * D / 4 + 255) / 256), dim3(256), 0, stream>>>(x, xb, T * D / 4);
  build_wdT<<<dim3((B * D + 255) / 256), dim3(256), 0, stream>>>(phm, W_down, wdT);
  build_wuT<<<dim3((D * B + 255) / 256), dim3(256), 0, stream>>>(phm, W_up, wuT);

  if (ws_size >= 76 * MB) {
    // GEMM1 split-K x4: P[c] = x @ Wd (K chunk c). grid 32x2x4 = 256
    gemm8p<2><<<dim3(256), dim3(512), 0, stream>>>(
        xb, wdT, b_down, P, D, D, 512, B, 32, 2, (size_t)T * B * sizeof(bf16));
    // z = relu(sum P + b_down)
    zred<<<dim3(T * B / 8 / 256), dim3(256), 0, stream>>>(P, b_down, z);
  } else {
    // fallback: single-pass GEMM1, grid 32x2 = 64
    gemm8p<0><<<dim3(64), dim3(512), 0, stream>>>(
        xb, wdT, b_down, z, D, D, D, B, 32, 2, 0);
  }

  // out = z @ Wu + b_up   [8192,2048] f32, grid 32x8 = 256
  gemm8p<1><<<dim3(256), dim3(512), 0, stream>>>(
      z, wuT, b_up, out, B, B, B, D, 32, 8, 0);
}